// Round 11
// baseline (30.828 us; speedup 1.0000x reference)
//
#include <hip/hip_runtime.h>

constexpr int KWIN = 100;
constexpr int HK   = 50;
constexpr int TSUB = 64;    // frames per thread (4 main batches of 16)
constexpr int MB   = 16;    // outputs per batch -> 48 loads per batch
constexpr int PB   = 20;    // prime batch -> 5 batches

template <bool REFLECT>
__device__ __forceinline__ int tidx(int t) {
    if constexpr (REFLECT) {
        constexpr int T = 16384;
        t = (t < 0) ? -t : t;
        return (t >= T) ? (2 * T - 2 - t) : t;
    }
    return t;   // interior chunk: linear addressing
}

template <bool REFLECT>
__device__ __forceinline__ void load_prime(const float* __restrict__ xb,
                                           const int t0, const int k,
                                           float p[PB]) {
    #pragma unroll
    for (int j = 0; j < PB; ++j)
        p[j] = xb[(size_t)tidx<REFLECT>(t0 - HK + k * PB + j) * 128];
}

__device__ __forceinline__ void acc_prime(const float p[PB],
                                          float& sx, float& sq) {
    #pragma unroll
    for (int j = 0; j < PB; ++j) {
        sx += p[j];
        sq  = fmaf(p[j], p[j], sq);
    }
}

template <bool REFLECT>
__device__ __forceinline__ void load_main(const float* __restrict__ xb,
                                          const int t0, const int tb,
                                          float c[MB], float o[MB], float g[MB]) {
    #pragma unroll
    for (int j = 0; j < MB; ++j) {
        const int t = t0 + tb + j;
        c[j] = xb[(size_t)t * 128];                       // x[t] never reflects
        o[j] = xb[(size_t)tidx<REFLECT>(t - HK) * 128];   // x[t-50]
        g[j] = xb[(size_t)tidx<REFLECT>(t + HK) * 128];   // x[t+50]
    }
}

__device__ __forceinline__ void compute_main(float* __restrict__ ob,
                                             const int t0, const int tb,
                                             const float c[MB], const float o[MB],
                                             const float g[MB],
                                             float& sx, float& sq) {
    const float invK   = 1.0f / (float)KWIN;
    const float invKm1 = 1.0f / (float)(KWIN - 1);
    const float fK     = (float)KWIN;
    #pragma unroll
    for (int j = 0; j < MB; ++j) {
        const float m  = sx * invK;
        const float va = fmaxf((sq - fK * m * m) * invKm1, 1e-24f);
        const float rs = __builtin_amdgcn_rsqf(va);       // v_rsq_f32
        __builtin_nontemporal_store((c[j] - m) * rs,
                                    &ob[(size_t)(t0 + tb + j) * 128]);
        sx += g[j] - o[j];
        sq += g[j] * g[j] - o[j] * o[j];
    }
}

template <bool REFLECT>
__device__ __forceinline__ void run_chunk(
    const float* __restrict__ xb, float* __restrict__ ob, const int t0)
{
    float sx = 0.f, sq = 0.f;

    // ---- prime: 5 batches of 20, software-pipelined 2-deep ----
    float pa[PB], pb_[PB];
    load_prime<REFLECT>(xb, t0, 0, pa);
    load_prime<REFLECT>(xb, t0, 1, pb_);
    acc_prime(pa, sx, sq);
    load_prime<REFLECT>(xb, t0, 2, pa);
    acc_prime(pb_, sx, sq);
    load_prime<REFLECT>(xb, t0, 3, pb_);
    acc_prime(pa, sx, sq);
    load_prime<REFLECT>(xb, t0, 4, pa);
    acc_prime(pb_, sx, sq);
    acc_prime(pa, sx, sq);

    // ---- main: 4 batches of 16 outputs, 2-deep: 96 loads in flight ----
    float cA[MB], oA[MB], gA[MB], cB[MB], oB[MB], gB[MB];
    load_main<REFLECT>(xb, t0, 0,      cA, oA, gA);
    load_main<REFLECT>(xb, t0, 1 * MB, cB, oB, gB);   // 96 loads outstanding
    compute_main(ob, t0, 0,      cA, oA, gA, sx, sq);
    load_main<REFLECT>(xb, t0, 2 * MB, cA, oA, gA);
    compute_main(ob, t0, 1 * MB, cB, oB, gB, sx, sq);
    load_main<REFLECT>(xb, t0, 3 * MB, cB, oB, gB);
    compute_main(ob, t0, 2 * MB, cA, oA, gA, sx, sq);
    compute_main(ob, t0, 3 * MB, cB, oB, gB, sx, sq);
}

__global__ __launch_bounds__(256, 2) void man_kernel(
    const float* __restrict__ x, float* __restrict__ out)
{
    constexpr int T = 16384, D = 128;

    const int i    = blockIdx.x;                  // 0..1023
    const int bb   = (i & 7) * 128 + (i >> 3);    // XCD (i&7) owns batch b
    const int b    = bb >> 7;                     // 0..7
    const int seg  = bb & 127;                    // pair of adjacent chunks
    const int w    = threadIdx.x >> 7;            // 0..1 chunk within pair
    const int tid  = threadIdx.x & 127;           // d column
    const int t0   = (seg * 2 + w) * TSUB;

    const float* __restrict__ xb = x   + (size_t)b * T * D + tid;
    float*       __restrict__ ob = out + (size_t)b * T * D + tid;

    if (t0 >= HK && t0 + TSUB - 1 + HK < T) {
        run_chunk<false>(xb, ob, t0);
    } else {
        run_chunk<true>(xb, ob, t0);
    }
}

extern "C" void kernel_launch(void* const* d_in, const int* in_sizes, int n_in,
                              void* d_out, int out_size, void* d_ws, size_t ws_size,
                              hipStream_t stream) {
    (void)in_sizes; (void)n_in; (void)d_ws; (void)ws_size; (void)out_size;
    const float* x = (const float*)d_in[0];
    float* out = (float*)d_out;
    // 8 b * 256 chunks * 128 d = 262144 threads = 1024 blocks * 256
    man_kernel<<<dim3(1024), dim3(256), 0, stream>>>(x, out);
}